// Round 7
// baseline (280.628 us; speedup 1.0000x reference)
//
#include <hip/hip_runtime.h>
#include <stdint.h>

typedef unsigned short u16;
typedef unsigned int   u32;

typedef float  f32x4  __attribute__((ext_vector_type(4)));
typedef __bf16 bf16x8 __attribute__((ext_vector_type(8)));

// ---------- helpers ----------
__device__ __forceinline__ u16 f2bf(float f) {
  union { float f; u32 u; } c; c.f = f;
  u32 u = c.u + 0x7fffu + ((c.u >> 16) & 1u);   // RNE; inputs finite
  return (u16)(u >> 16);
}
__device__ __forceinline__ float bf2f(u16 h) {
  union { u32 u; float f; } c; c.u = ((u32)h) << 16;
  return c.f;
}
__device__ __forceinline__ void gll16(const void* g, void* l) {
  __builtin_amdgcn_global_load_lds(
      (const __attribute__((address_space(1))) void*)g,
      (__attribute__((address_space(3))) void*)l, 16, 0, 0);
}

// ---------- prep: fused conv13(x)->y(bf16) + Wi/Wo f32->bf16 -------------
// Linearity: attended = conv_h(x @ Wi^T) = conv_h(x) @ Wi^T. All heads share
// the center Gaussian; head differences are l-shifts (+-1) or constant rows
// (first/last). y[b, l'] computed for l' in [-1, 2048] (2050 rows/batch) so
// every head's shift is an exact row lookup, edge renormalization included
// (same zero-invalid-taps + Z-renorm arithmetic as the verified gauss_conv).
__global__ __launch_bounds__(256)
void prep(const float* __restrict__ x, u16* __restrict__ y,
          const float4* __restrict__ wi, uint2* __restrict__ wib,
          const float4* __restrict__ wo, uint2* __restrict__ wob,
          int nconvb, int L) {
  constexpr float wt[13] = {
    1.5229979744712628e-08f, 3.7266531720786709e-06f, 3.3546262790251185e-04f,
    1.1108996538242306e-02f, 1.3533528323661270e-01f, 6.0653065971263342e-01f,
    1.0f,
    6.0653065971263342e-01f, 1.3533528323661270e-01f, 1.1108996538242306e-02f,
    3.3546262790251185e-04f, 3.7266531720786709e-06f, 1.5229979744712628e-08f
  };
  const int t = threadIdx.x;
  if ((int)blockIdx.x >= nconvb) {                // ---- W convert tail ----
    int wid = ((int)blockIdx.x - nconvb) * 256 + t;
    const int n4w = 1024 * 1024 / 4;
    const float4* s; uint2* d; int j;
    if (wid < n4w) { s = wi; d = wib; j = wid; }
    else           { s = wo; d = wob; j = wid - n4w; }
    float4 v = s[j];
    uint2 o;
    o.x = (u32)f2bf(v.x) | ((u32)f2bf(v.y) << 16);
    o.y = (u32)f2bf(v.z) | ((u32)f2bf(v.w) << 16);
    d[j] = o;
    return;
  }
  // ---- conv: one thread = 8 feats of one y row ----
  int id    = (int)blockIdx.x * 256 + t;
  int fg    = id & 127;                           // feature-group (8 f32)
  int rowid = id >> 7;                            // b*2050 + (l'+1)
  int b     = rowid / 2050;
  int lp    = rowid - b * 2050 - 1;               // l' in [-1, L]
  const float* xb = x + (size_t)b * L * 1024 + fg * 8;
  float a[8] = {};
  float Z = 0.f;
#pragma unroll
  for (int d = -6; d <= 6; ++d) {
    int idx = lp + d;
    bool ok = (idx >= 0) && (idx < L);
    int ic  = idx < 0 ? 0 : (idx >= L ? L - 1 : idx);
    float w = ok ? wt[d + 6] : 0.f;
    Z += w;
    const float4* p = reinterpret_cast<const float4*>(xb + (size_t)ic * 1024);
    float4 p0 = p[0], p1 = p[1];
    a[0] = fmaf(w, p0.x, a[0]); a[1] = fmaf(w, p0.y, a[1]);
    a[2] = fmaf(w, p0.z, a[2]); a[3] = fmaf(w, p0.w, a[3]);
    a[4] = fmaf(w, p1.x, a[4]); a[5] = fmaf(w, p1.y, a[5]);
    a[6] = fmaf(w, p1.z, a[6]); a[7] = fmaf(w, p1.w, a[7]);
  }
  float inv = 1.0f / Z;
  uint4 o;
  o.x = (u32)f2bf(a[0] * inv) | ((u32)f2bf(a[1] * inv) << 16);
  o.y = (u32)f2bf(a[2] * inv) | ((u32)f2bf(a[3] * inv) << 16);
  o.z = (u32)f2bf(a[4] * inv) | ((u32)f2bf(a[5] * inv) << 16);
  o.w = (u32)f2bf(a[6] * inv) | ((u32)f2bf(a[7] * inv) << 16);
  *reinterpret_cast<uint4*>(y + (size_t)rowid * 1024 + fg * 8) = o;
}

// ---------- bf16 NT GEMM: C[M,N] = A[M,K] * B[N,K]^T (r0 proven, 904 TF) --
// 128x128 tile, BK=64, 4 waves, XOR-swizzled chunk placement on the GLOBAL
// side (global_load_lds lane-contiguous dest preserved), grid (8, M/128)
// with XCD swizzle. AMODE 0: A rows direct (stride K). AMODE 1: A = y
// (stride 1024 = K), rows remapped per head h = n-tile: center l+1, left l,
// right l+2, first 1, last 2048 (y row index = b*2050 + shift; rows never
// cross a batch boundary since 2048 % 128 == 0). Remap cost: 4 precomputed
// base pointers, zero inner-loop overhead.
template <int AMODE, bool OUT_BF16>
__global__ __launch_bounds__(256, 4)
void gemm_nt_bf16(const u16* __restrict__ A, const u16* __restrict__ B,
                  void* __restrict__ Cout, int M, int N, int K) {
  __shared__ u16 As[128 * 64];   // 16 KB each; row stride 64 u16 = 128 B
  __shared__ u16 Bs[128 * 64];
  const int t    = threadIdx.x;
  const int lane = t & 63;
  const int ml   = lane & 15;
  const int q    = lane >> 4;
  const int wave = t >> 6;
  const int wm   = wave >> 1;
  const int wn   = wave & 1;

  // ---- XCD-locality swizzle (bijection; gridDim.x == 8) ----
  const int flat    = blockIdx.y * 8 + blockIdx.x;
  const int xcd     = flat & 7;
  const int slot    = flat >> 3;
  const int per_xcd = gridDim.y >> 3;
  const int mt      = xcd * per_xcd + (slot >> 3);
  const int nt      = slot & 7;
  const int m0      = mt * 128;
  const int n0      = nt * 128;

  f32x4 acc[4][4] = {};

  // staging: thread t, j=0..3 stages chunk id c = t + 256j:
  //   LDS byte = c*16 (row sr=c>>3, slot-chunk c&7); global chunk = (c&7)^(sr&7)
  const int sr = t >> 3;                             // 0..31 (+32j per j)
  const int gk = (((t & 7) ^ (sr & 7)) * 8);         // global k-offset (u16)
  const u16* Agj[4];
#pragma unroll
  for (int j = 0; j < 4; ++j) {
    const int mr = m0 + sr + 32 * j;
    size_t arow;
    if (AMODE == 0) {
      arow = (size_t)mr;
    } else {
      const int b = mr >> 11, l = mr & 2047;
      const int h = n0 >> 7;                         // head == n-tile
      int sfl;
      switch (h) {
        case 0: case 5: sfl = l + 1; break;          // center
        case 1: case 6: sfl = l;     break;          // left  -> y[l-1]
        case 2: case 7: sfl = l + 2; break;          // right -> y[l+1]
        case 3:         sfl = 1;     break;          // first -> y[0]
        default:        sfl = 2048;  break;          // last  -> y[L-1]
      }
      arow = (size_t)b * 2050 + sfl;
    }
    Agj[j] = A + arow * K + gk;
  }
  const u16* Bg = B + (size_t)(n0 + sr) * K + gk;
  const int wb = (t & 192) * 16;                     // wave-uniform byte base
  char* AsB = (char*)As;
  char* BsB = (char*)Bs;

  for (int k0 = 0; k0 < K; k0 += 64) {
#pragma unroll
    for (int j = 0; j < 4; ++j) {
      gll16(Agj[j] + k0, AsB + j * 4096 + wb);
      gll16(Bg + (size_t)(32 * j) * K + k0, BsB + j * 4096 + wb);
    }
    __syncthreads();
#pragma unroll
    for (int s = 0; s < 2; ++s) {       // two k=32 sub-steps
      bf16x8 af[4], bfv[4];
#pragma unroll
      for (int i = 0; i < 4; ++i) {
        const int R = wm * 64 + i * 16 + ml;
        af[i] = *reinterpret_cast<const bf16x8*>(
            &As[R * 64 + (((s * 4 + q) ^ (R & 7)) * 8)]);
      }
#pragma unroll
      for (int i = 0; i < 4; ++i) {
        const int R = wn * 64 + i * 16 + ml;
        bfv[i] = *reinterpret_cast<const bf16x8*>(
            &Bs[R * 64 + (((s * 4 + q) ^ (R & 7)) * 8)]);
      }
#pragma unroll
      for (int i = 0; i < 4; ++i)
#pragma unroll
        for (int j = 0; j < 4; ++j)
          acc[i][j] = __builtin_amdgcn_mfma_f32_16x16x32_bf16(af[i], bfv[j], acc[i][j], 0, 0, 0);
    }
    __syncthreads();
  }

  // epilogue: C/D frag row = q*4 + reg, col = lane&15 (verified m89/m91)
  const int rowb = m0 + wm * 64 + q * 4;
  const int colb = n0 + wn * 64 + ml;
#pragma unroll
  for (int i = 0; i < 4; ++i)
#pragma unroll
    for (int j = 0; j < 4; ++j)
#pragma unroll
      for (int r = 0; r < 4; ++r) {
        size_t idx = (size_t)(rowb + i * 16 + r) * N + (colb + j * 16);
        float val = acc[i][j][r];
        if (OUT_BF16) ((u16*)Cout)[idx] = f2bf(val);
        else          ((float*)Cout)[idx] = val;
      }
}

// ---------- launch ----------
extern "C" void kernel_launch(void* const* d_in, const int* in_sizes, int n_in,
                              void* d_out, int out_size, void* d_ws, size_t ws_size,
                              hipStream_t stream) {
  const int Bb = 8, L = 2048, E = 1024;
  const int M = Bb * L, N = E, K = E;

  const float* x  = (const float*)d_in[0];
  const float* Wi = (const float*)d_in[1];
  const float* Wo = (const float*)d_in[2];
  float* out = (float*)d_out;

  // ws layout (bf16): [y 8*2050 rows | v' 32Mi | wib 2Mi | wob 2Mi]
  size_t offV  = (size_t)Bb * 2050 * E * 2;        // 33,587,200 B (256-aligned)
  size_t offWi = offV + (size_t)M * E * 2;
  size_t offWo = offWi + (size_t)E * E * 2;
  size_t need  = offWo + (size_t)E * E * 2;
  if (ws_size < need) return;

  u16* y   = (u16*)d_ws;
  u16* v   = (u16*)((char*)d_ws + offV);
  u16* wib = (u16*)((char*)d_ws + offWi);
  u16* wob = (u16*)((char*)d_ws + offWo);

  // prep: conv blocks + W-convert blocks in one dispatch
  const int nconvb = Bb * 2050 * (E / 8) / 256;    // 8200
  const int nwb    = 2 * (E * E / 4) / 256;        // 2048
  prep<<<nconvb + nwb, 256, 0, stream>>>(x, y, (const float4*)Wi, (uint2*)wib,
                                         (const float4*)Wo, (uint2*)wob, nconvb, L);

  dim3 gg(N / 128, M / 128);   // (8, 128) — swizzle in-kernel assumes x==8
  gemm_nt_bf16<1, true ><<<gg, 256, 0, stream>>>(y, wib, v,   M, N, K);
  gemm_nt_bf16<0, false><<<gg, 256, 0, stream>>>(v, wob, out, M, N, K);
}

// Round 8
// 236.053 us; speedup vs baseline: 1.1888x; 1.1888x over previous
//
#include <hip/hip_runtime.h>
#include <stdint.h>

typedef unsigned short u16;
typedef unsigned int   u32;

typedef float  f32x4  __attribute__((ext_vector_type(4)));
typedef __bf16 bf16x8 __attribute__((ext_vector_type(8)));

// ---------- helpers ----------
__device__ __forceinline__ u16 f2bf(float f) {
  union { float f; u32 u; } c; c.f = f;
  u32 u = c.u + 0x7fffu + ((c.u >> 16) & 1u);   // RNE; inputs finite
  return (u16)(u >> 16);
}
__device__ __forceinline__ float bf2f(u16 h) {
  union { u32 u; float f; } c; c.u = ((u32)h) << 16;
  return c.f;
}
__device__ __forceinline__ void gll16(const void* g, void* l) {
  __builtin_amdgcn_global_load_lds(
      (const __attribute__((address_space(1))) void*)g,
      (__attribute__((address_space(3))) void*)l, 16, 0, 0);
}

// ---------- prep: fused conv13(x)->y(bf16) + Wi/Wo f32->bf16 -------------
// Linearity: attended = conv_h(x @ Wi^T) = conv_h(x) @ Wi^T (heads differ
// only by l-shift / constant row). y[b, l'] for l' in [-1, 2048] (2050 rows)
// so every head's shift is an exact row lookup, edge renorm included.
// Round-8 locality fix (r7: FETCH 417MB = 6.5x input, 119us): block =
// 32 l'-rows x 64-feat slice (256 thr = 32 rows x 8 fg). Unique bytes/block
// = 44 rows x 256B = 11KB (fits 32KB L1 -> 13-tap overlap is L1-served);
// halo ratio 44/32 = 1.375 -> ~90MB total fetch instead of 417MB. r7's
// 2-row x 1024-feat blocks had 7x within-block re-read with cross-XCD halo.
__global__ __launch_bounds__(256)
void prep(const float* __restrict__ x, u16* __restrict__ y,
          const float4* __restrict__ wi, uint2* __restrict__ wib,
          const float4* __restrict__ wo, uint2* __restrict__ wob,
          int nconvb, int L) {
  constexpr float wt[13] = {
    1.5229979744712628e-08f, 3.7266531720786709e-06f, 3.3546262790251185e-04f,
    1.1108996538242306e-02f, 1.3533528323661270e-01f, 6.0653065971263342e-01f,
    1.0f,
    6.0653065971263342e-01f, 1.3533528323661270e-01f, 1.1108996538242306e-02f,
    3.3546262790251185e-04f, 3.7266531720786709e-06f, 1.5229979744712628e-08f
  };
  const int t = threadIdx.x;
  if ((int)blockIdx.x >= nconvb) {                // ---- W convert tail ----
    int wid = ((int)blockIdx.x - nconvb) * 256 + t;
    const int n4w = 1024 * 1024 / 4;
    const float4* s; uint2* d; int j;
    if (wid < n4w) { s = wi; d = wib; j = wid; }
    else           { s = wo; d = wob; j = wid - n4w; }
    float4 v = s[j];
    uint2 o;
    o.x = (u32)f2bf(v.x) | ((u32)f2bf(v.y) << 16);
    o.y = (u32)f2bf(v.z) | ((u32)f2bf(v.w) << 16);
    d[j] = o;
    return;
  }
  // ---- conv: block = (b, row-chunk, feat-slice); thread = (row, fg8) ----
  const int id    = (int)blockIdx.x;
  const int b     = id / (65 * 16);
  const int rem   = id - b * (65 * 16);
  const int chunk = rem >> 4;                     // 0..64 (32 rows each)
  const int slice = rem & 15;                     // 0..15 (64 feats each)
  const int li    = t >> 3;                       // 0..31
  const int fj    = t & 7;                        // 0..7  (8 f32 each)
  const int rloc  = chunk * 32 + li;              // row within batch grid
  if (rloc >= 2050) return;                       // tail guard
  const int lp    = rloc - 1;                     // l' in [-1, L]
  const int fbase = slice * 64 + fj * 8;
  const float* xb = x + (size_t)b * L * 1024 + fbase;

  float a[8] = {};
  float Z = 0.f;
#pragma unroll
  for (int d = -6; d <= 6; ++d) {
    int idx = lp + d;
    bool ok = (idx >= 0) && (idx < L);
    int ic  = idx < 0 ? 0 : (idx >= L ? L - 1 : idx);
    float w = ok ? wt[d + 6] : 0.f;
    Z += w;
    const float4* p = reinterpret_cast<const float4*>(xb + (size_t)ic * 1024);
    float4 p0 = p[0], p1 = p[1];
    a[0] = fmaf(w, p0.x, a[0]); a[1] = fmaf(w, p0.y, a[1]);
    a[2] = fmaf(w, p0.z, a[2]); a[3] = fmaf(w, p0.w, a[3]);
    a[4] = fmaf(w, p1.x, a[4]); a[5] = fmaf(w, p1.y, a[5]);
    a[6] = fmaf(w, p1.z, a[6]); a[7] = fmaf(w, p1.w, a[7]);
  }
  float inv = 1.0f / Z;
  uint4 o;
  o.x = (u32)f2bf(a[0] * inv) | ((u32)f2bf(a[1] * inv) << 16);
  o.y = (u32)f2bf(a[2] * inv) | ((u32)f2bf(a[3] * inv) << 16);
  o.z = (u32)f2bf(a[4] * inv) | ((u32)f2bf(a[5] * inv) << 16);
  o.w = (u32)f2bf(a[6] * inv) | ((u32)f2bf(a[7] * inv) << 16);
  *reinterpret_cast<uint4*>(y + (size_t)(b * 2050 + rloc) * 1024 + fbase) = o;
}

// ---------- bf16 NT GEMM: C[M,N] = A[M,K] * B[N,K]^T (r0 proven, 904 TF) --
// 128x128 tile, BK=64, 4 waves, XOR-swizzled chunk placement on the GLOBAL
// side (global_load_lds lane-contiguous dest preserved), grid (8, M/128)
// with XCD swizzle. AMODE 0: A rows direct (stride K). AMODE 1: A = y
// (stride 1024 = K), rows remapped per head h = n-tile: center l+1, left l,
// right l+2, first 1, last 2048 (y row index = b*2050 + shift; rows never
// cross a batch boundary since 2048 % 128 == 0). Remap cost: 4 precomputed
// base pointers, zero inner-loop overhead.
template <int AMODE, bool OUT_BF16>
__global__ __launch_bounds__(256, 4)
void gemm_nt_bf16(const u16* __restrict__ A, const u16* __restrict__ B,
                  void* __restrict__ Cout, int M, int N, int K) {
  __shared__ u16 As[128 * 64];   // 16 KB each; row stride 64 u16 = 128 B
  __shared__ u16 Bs[128 * 64];
  const int t    = threadIdx.x;
  const int lane = t & 63;
  const int ml   = lane & 15;
  const int q    = lane >> 4;
  const int wave = t >> 6;
  const int wm   = wave >> 1;
  const int wn   = wave & 1;

  // ---- XCD-locality swizzle (bijection; gridDim.x == 8) ----
  const int flat    = blockIdx.y * 8 + blockIdx.x;
  const int xcd     = flat & 7;
  const int slot    = flat >> 3;
  const int per_xcd = gridDim.y >> 3;
  const int mt      = xcd * per_xcd + (slot >> 3);
  const int nt      = slot & 7;
  const int m0      = mt * 128;
  const int n0      = nt * 128;

  f32x4 acc[4][4] = {};

  // staging: thread t, j=0..3 stages chunk id c = t + 256j:
  //   LDS byte = c*16 (row sr=c>>3, slot-chunk c&7); global chunk = (c&7)^(sr&7)
  const int sr = t >> 3;                             // 0..31 (+32j per j)
  const int gk = (((t & 7) ^ (sr & 7)) * 8);         // global k-offset (u16)
  const u16* Agj[4];
#pragma unroll
  for (int j = 0; j < 4; ++j) {
    const int mr = m0 + sr + 32 * j;
    size_t arow;
    if (AMODE == 0) {
      arow = (size_t)mr;
    } else {
      const int b = mr >> 11, l = mr & 2047;
      const int h = n0 >> 7;                         // head == n-tile
      int sfl;
      switch (h) {
        case 0: case 5: sfl = l + 1; break;          // center
        case 1: case 6: sfl = l;     break;          // left  -> y[l-1]
        case 2: case 7: sfl = l + 2; break;          // right -> y[l+1]
        case 3:         sfl = 1;     break;          // first -> y[0]
        default:        sfl = 2048;  break;          // last  -> y[L-1]
      }
      arow = (size_t)b * 2050 + sfl;
    }
    Agj[j] = A + arow * K + gk;
  }
  const u16* Bg = B + (size_t)(n0 + sr) * K + gk;
  const int wb = (t & 192) * 16;                     // wave-uniform byte base
  char* AsB = (char*)As;
  char* BsB = (char*)Bs;

  for (int k0 = 0; k0 < K; k0 += 64) {
#pragma unroll
    for (int j = 0; j < 4; ++j) {
      gll16(Agj[j] + k0, AsB + j * 4096 + wb);
      gll16(Bg + (size_t)(32 * j) * K + k0, BsB + j * 4096 + wb);
    }
    __syncthreads();
#pragma unroll
    for (int s = 0; s < 2; ++s) {       // two k=32 sub-steps
      bf16x8 af[4], bfv[4];
#pragma unroll
      for (int i = 0; i < 4; ++i) {
        const int R = wm * 64 + i * 16 + ml;
        af[i] = *reinterpret_cast<const bf16x8*>(
            &As[R * 64 + (((s * 4 + q) ^ (R & 7)) * 8)]);
      }
#pragma unroll
      for (int i = 0; i < 4; ++i) {
        const int R = wn * 64 + i * 16 + ml;
        bfv[i] = *reinterpret_cast<const bf16x8*>(
            &Bs[R * 64 + (((s * 4 + q) ^ (R & 7)) * 8)]);
      }
#pragma unroll
      for (int i = 0; i < 4; ++i)
#pragma unroll
        for (int j = 0; j < 4; ++j)
          acc[i][j] = __builtin_amdgcn_mfma_f32_16x16x32_bf16(af[i], bfv[j], acc[i][j], 0, 0, 0);
    }
    __syncthreads();
  }

  // epilogue: C/D frag row = q*4 + reg, col = lane&15 (verified m89/m91)
  const int rowb = m0 + wm * 64 + q * 4;
  const int colb = n0 + wn * 64 + ml;
#pragma unroll
  for (int i = 0; i < 4; ++i)
#pragma unroll
    for (int j = 0; j < 4; ++j)
#pragma unroll
      for (int r = 0; r < 4; ++r) {
        size_t idx = (size_t)(rowb + i * 16 + r) * N + (colb + j * 16);
        float val = acc[i][j][r];
        if (OUT_BF16) ((u16*)Cout)[idx] = f2bf(val);
        else          ((float*)Cout)[idx] = val;
      }
}

// ---------- launch ----------
extern "C" void kernel_launch(void* const* d_in, const int* in_sizes, int n_in,
                              void* d_out, int out_size, void* d_ws, size_t ws_size,
                              hipStream_t stream) {
  const int Bb = 8, L = 2048, E = 1024;
  const int M = Bb * L, N = E, K = E;

  const float* x  = (const float*)d_in[0];
  const float* Wi = (const float*)d_in[1];
  const float* Wo = (const float*)d_in[2];
  float* out = (float*)d_out;

  // ws layout (bf16): [y 8*2050 rows | v' 32Mi | wib 2Mi | wob 2Mi]
  size_t offV  = (size_t)Bb * 2050 * E * 2;        // 33,587,200 B (256-aligned)
  size_t offWi = offV + (size_t)M * E * 2;
  size_t offWo = offWi + (size_t)E * E * 2;
  size_t need  = offWo + (size_t)E * E * 2;
  if (ws_size < need) return;

  u16* y   = (u16*)d_ws;
  u16* v   = (u16*)((char*)d_ws + offV);
  u16* wib = (u16*)((char*)d_ws + offWi);
  u16* wob = (u16*)((char*)d_ws + offWo);

  // prep: conv blocks (8 batches x 65 chunks x 16 slices) + W-convert tail
  const int nconvb = Bb * 65 * 16;                 // 8320
  const int nwb    = 2 * (E * E / 4) / 256;        // 2048
  prep<<<nconvb + nwb, 256, 0, stream>>>(x, y, (const float4*)Wi, (uint2*)wib,
                                         (const float4*)Wo, (uint2*)wob, nconvb, L);

  dim3 gg(N / 128, M / 128);   // (8, 128) — swizzle in-kernel assumes x==8
  gemm_nt_bf16<1, true ><<<gg, 256, 0, stream>>>(y, wib, v,   M, N, K);
  gemm_nt_bf16<0, false><<<gg, 256, 0, stream>>>(v, wob, out, M, N, K);
}

// Round 9
// 191.027 us; speedup vs baseline: 1.4690x; 1.2357x over previous
//
#include <hip/hip_runtime.h>
#include <stdint.h>

typedef unsigned short u16;
typedef unsigned int   u32;

typedef float  f32x4  __attribute__((ext_vector_type(4)));
typedef __bf16 bf16x8 __attribute__((ext_vector_type(8)));

// ---------- helpers ----------
__device__ __forceinline__ u16 f2bf(float f) {
  union { float f; u32 u; } c; c.f = f;
  u32 u = c.u + 0x7fffu + ((c.u >> 16) & 1u);   // RNE; inputs finite
  return (u16)(u >> 16);
}
__device__ __forceinline__ void gll16(const void* g, void* l) {
  __builtin_amdgcn_global_load_lds(
      (const __attribute__((address_space(1))) void*)g,
      (__attribute__((address_space(3))) void*)l, 16, 0, 0);
}

// ---------- prep: fused conv13(x)->y(bf16) + Wi/Wo f32->bf16 -------------
// Linearity: attended = conv_h(x @ Wi^T) = conv_h(x) @ Wi^T (heads differ
// only by l-shift / constant row). y[b, l'] for l' in [-1, 2048] (2050 rows)
// so every head's shift is an exact row lookup, edge renorm included.
// Round-9 fix (r8 was latency-bound: 71us, all pipes idle -- 13x tap
// re-reads thrashed L1/L2, served from ~500cy L3 with ~5 loads in flight):
// stage the conv window in LDS, read x ONCE from global.
//   block = 32 output rows x 256-feat slice; window = 44 rows x 1KB = 44KB
//   staging: global_load_lds, wave = one row (uniform base + lane*16, the
//            gll-legal linear pattern), 11 issues/wave.
//   compute: wave owns one output row; lane = 16B granule; 13 taps of
//            stride-1 ds_read_b128 (conflict-free) + 4 FMA each.
// Arithmetic per output element is order-identical to the r7/r8 passing
// conv (staged row = clamp(lp+d); fmaf in d order; w=0 outside; Z-renorm).
__global__ __launch_bounds__(256)
void prep(const float* __restrict__ x, u16* __restrict__ y,
          const float4* __restrict__ wi, uint2* __restrict__ wib,
          const float4* __restrict__ wo, uint2* __restrict__ wob,
          int nconvb, int L) {
  constexpr float wt[13] = {
    1.5229979744712628e-08f, 3.7266531720786709e-06f, 3.3546262790251185e-04f,
    1.1108996538242306e-02f, 1.3533528323661270e-01f, 6.0653065971263342e-01f,
    1.0f,
    6.0653065971263342e-01f, 1.3533528323661270e-01f, 1.1108996538242306e-02f,
    3.3546262790251185e-04f, 3.7266531720786709e-06f, 1.5229979744712628e-08f
  };
  __shared__ float Xs[44 * 256];                  // 44 rows x 1KB = 44KB
  const int t = threadIdx.x;
  if ((int)blockIdx.x >= nconvb) {                // ---- W convert tail ----
    int wid = ((int)blockIdx.x - nconvb) * 256 + t;
    const int n4w = 1024 * 1024 / 4;
    const float4* s; uint2* d; int j;
    if (wid < n4w) { s = wi; d = wib; j = wid; }
    else           { s = wo; d = wob; j = wid - n4w; }
    float4 v = s[j];
    uint2 o;
    o.x = (u32)f2bf(v.x) | ((u32)f2bf(v.y) << 16);
    o.y = (u32)f2bf(v.z) | ((u32)f2bf(v.w) << 16);
    d[j] = o;
    return;
  }
  // ---- decode: block = (b, row-chunk, feat-slice 256) ----
  const int id    = (int)blockIdx.x;
  const int b     = id / 260;                     // 65 chunks x 4 slices
  const int rem   = id - b * 260;
  const int chunk = rem >> 2;                     // 0..64 (32 rows each)
  const int slice = rem & 3;                      // 0..3  (256 f32 each)
  const int w_    = t >> 6;                       // wave 0..3
  const int g     = t & 63;                       // 16B granule within row
  const int lp0   = chunk * 32 - 1;               // first output l'

  // ---- stage 44-row window (rows lp0-6 .. lp0+37, clamped) ----
  const char* xb = (const char*)x + ((size_t)b << 23);   // b*2048*4096
  char* XsB = (char*)Xs;
#pragma unroll
  for (int j = 0; j < 11; ++j) {
    const int lr = j * 4 + w_;                    // wave-uniform local row
    int gr = lp0 - 6 + lr;
    gr = gr < 0 ? 0 : (gr >= L ? L - 1 : gr);
    gll16(xb + ((size_t)gr << 12) + (slice << 10) + g * 16,
          XsB + lr * 1024);
  }
  asm volatile("s_waitcnt vmcnt(0)" ::: "memory");
  __syncthreads();

  // ---- compute: wave = one output row at a time (8 rows/wave) ----
  for (int rr = 0; rr < 8; ++rr) {
    const int orow = rr * 4 + w_;                 // 0..31, wave-uniform
    const int rloc = chunk * 32 + orow;
    if (rloc >= 2050) continue;
    const int lp = rloc - 1;
    float a0 = 0.f, a1 = 0.f, a2 = 0.f, a3 = 0.f;
    float Z = 0.f;
#pragma unroll
    for (int d = -6; d <= 6; ++d) {
      const int idx = lp + d;
      const bool ok = (idx >= 0) && (idx < L);
      const float wv = ok ? wt[d + 6] : 0.f;
      Z += wv;
      const int lr = orow + d + 6;                // 0..43
      f32x4 v = *reinterpret_cast<const f32x4*>(&Xs[lr * 256 + g * 4]);
      a0 = fmaf(wv, v[0], a0);
      a1 = fmaf(wv, v[1], a1);
      a2 = fmaf(wv, v[2], a2);
      a3 = fmaf(wv, v[3], a3);
    }
    const float inv = 1.0f / Z;
    uint2 o;
    o.x = (u32)f2bf(a0 * inv) | ((u32)f2bf(a1 * inv) << 16);
    o.y = (u32)f2bf(a2 * inv) | ((u32)f2bf(a3 * inv) << 16);
    *reinterpret_cast<uint2*>(
        y + (size_t)(b * 2050 + rloc) * 1024 + slice * 256 + g * 4) = o;
  }
}

// ---------- bf16 NT GEMM: C[M,N] = A[M,K] * B[N,K]^T (r0 proven, 904 TF) --
// 128x128 tile, BK=64, 4 waves, XOR-swizzled chunk placement on the GLOBAL
// side (global_load_lds lane-contiguous dest preserved), grid (8, M/128)
// with XCD swizzle. AMODE 0: A rows direct (stride K). AMODE 1: A = y
// (stride 1024 = K), rows remapped per head h = n-tile: center l+1, left l,
// right l+2, first 1, last 2048 (y row index = b*2050 + shift; rows never
// cross a batch boundary since 2048 % 128 == 0). Remap cost: 4 precomputed
// base pointers, zero inner-loop overhead.
template <int AMODE, bool OUT_BF16>
__global__ __launch_bounds__(256, 4)
void gemm_nt_bf16(const u16* __restrict__ A, const u16* __restrict__ B,
                  void* __restrict__ Cout, int M, int N, int K) {
  __shared__ u16 As[128 * 64];   // 16 KB each; row stride 64 u16 = 128 B
  __shared__ u16 Bs[128 * 64];
  const int t    = threadIdx.x;
  const int lane = t & 63;
  const int ml   = lane & 15;
  const int q    = lane >> 4;
  const int wave = t >> 6;
  const int wm   = wave >> 1;
  const int wn   = wave & 1;

  // ---- XCD-locality swizzle (bijection; gridDim.x == 8) ----
  const int flat    = blockIdx.y * 8 + blockIdx.x;
  const int xcd     = flat & 7;
  const int slot    = flat >> 3;
  const int per_xcd = gridDim.y >> 3;
  const int mt      = xcd * per_xcd + (slot >> 3);
  const int nt      = slot & 7;
  const int m0      = mt * 128;
  const int n0      = nt * 128;

  f32x4 acc[4][4] = {};

  // staging: thread t, j=0..3 stages chunk id c = t + 256j:
  //   LDS byte = c*16 (row sr=c>>3, slot-chunk c&7); global chunk = (c&7)^(sr&7)
  const int sr = t >> 3;                             // 0..31 (+32j per j)
  const int gk = (((t & 7) ^ (sr & 7)) * 8);         // global k-offset (u16)
  const u16* Agj[4];
#pragma unroll
  for (int j = 0; j < 4; ++j) {
    const int mr = m0 + sr + 32 * j;
    size_t arow;
    if (AMODE == 0) {
      arow = (size_t)mr;
    } else {
      const int b = mr >> 11, l = mr & 2047;
      const int h = n0 >> 7;                         // head == n-tile
      int sfl;
      switch (h) {
        case 0: case 5: sfl = l + 1; break;          // center
        case 1: case 6: sfl = l;     break;          // left  -> y[l-1]
        case 2: case 7: sfl = l + 2; break;          // right -> y[l+1]
        case 3:         sfl = 1;     break;          // first -> y[0]
        default:        sfl = 2048;  break;          // last  -> y[L-1]
      }
      arow = (size_t)b * 2050 + sfl;
    }
    Agj[j] = A + arow * K + gk;
  }
  const u16* Bg = B + (size_t)(n0 + sr) * K + gk;
  const int wb = (t & 192) * 16;                     // wave-uniform byte base
  char* AsB = (char*)As;
  char* BsB = (char*)Bs;

  for (int k0 = 0; k0 < K; k0 += 64) {
#pragma unroll
    for (int j = 0; j < 4; ++j) {
      gll16(Agj[j] + k0, AsB + j * 4096 + wb);
      gll16(Bg + (size_t)(32 * j) * K + k0, BsB + j * 4096 + wb);
    }
    __syncthreads();
#pragma unroll
    for (int s = 0; s < 2; ++s) {       // two k=32 sub-steps
      bf16x8 af[4], bfv[4];
#pragma unroll
      for (int i = 0; i < 4; ++i) {
        const int R = wm * 64 + i * 16 + ml;
        af[i] = *reinterpret_cast<const bf16x8*>(
            &As[R * 64 + (((s * 4 + q) ^ (R & 7)) * 8)]);
      }
#pragma unroll
      for (int i = 0; i < 4; ++i) {
        const int R = wn * 64 + i * 16 + ml;
        bfv[i] = *reinterpret_cast<const bf16x8*>(
            &Bs[R * 64 + (((s * 4 + q) ^ (R & 7)) * 8)]);
      }
#pragma unroll
      for (int i = 0; i < 4; ++i)
#pragma unroll
        for (int j = 0; j < 4; ++j)
          acc[i][j] = __builtin_amdgcn_mfma_f32_16x16x32_bf16(af[i], bfv[j], acc[i][j], 0, 0, 0);
    }
    __syncthreads();
  }

  // epilogue: C/D frag row = q*4 + reg, col = lane&15 (verified m89/m91)
  const int rowb = m0 + wm * 64 + q * 4;
  const int colb = n0 + wn * 64 + ml;
#pragma unroll
  for (int i = 0; i < 4; ++i)
#pragma unroll
    for (int j = 0; j < 4; ++j)
#pragma unroll
      for (int r = 0; r < 4; ++r) {
        size_t idx = (size_t)(rowb + i * 16 + r) * N + (colb + j * 16);
        float val = acc[i][j][r];
        if (OUT_BF16) ((u16*)Cout)[idx] = f2bf(val);
        else          ((float*)Cout)[idx] = val;
      }
}

// ---------- launch ----------
extern "C" void kernel_launch(void* const* d_in, const int* in_sizes, int n_in,
                              void* d_out, int out_size, void* d_ws, size_t ws_size,
                              hipStream_t stream) {
  const int Bb = 8, L = 2048, E = 1024;
  const int M = Bb * L, N = E, K = E;

  const float* x  = (const float*)d_in[0];
  const float* Wi = (const float*)d_in[1];
  const float* Wo = (const float*)d_in[2];
  float* out = (float*)d_out;

  // ws layout (bf16): [y 8*2050 rows | v' 32Mi | wib 2Mi | wob 2Mi]
  size_t offV  = (size_t)Bb * 2050 * E * 2;        // 33,587,200 B (256-aligned)
  size_t offWi = offV + (size_t)M * E * 2;
  size_t offWo = offWi + (size_t)E * E * 2;
  size_t need  = offWo + (size_t)E * E * 2;
  if (ws_size < need) return;

  u16* y   = (u16*)d_ws;
  u16* v   = (u16*)((char*)d_ws + offV);
  u16* wib = (u16*)((char*)d_ws + offWi);
  u16* wob = (u16*)((char*)d_ws + offWo);

  // prep: conv blocks (8 batches x 65 chunks x 4 slices) + W-convert tail
  const int nconvb = Bb * 65 * 4;                  // 2080
  const int nwb    = 2 * (E * E / 4) / 256;        // 2048
  prep<<<nconvb + nwb, 256, 0, stream>>>(x, y, (const float4*)Wi, (uint2*)wib,
                                         (const float4*)Wo, (uint2*)wob, nconvb, L);

  dim3 gg(N / 128, M / 128);   // (8, 128) — swizzle in-kernel assumes x==8
  gemm_nt_bf16<1, true ><<<gg, 256, 0, stream>>>(y, wib, v,   M, N, K);
  gemm_nt_bf16<0, false><<<gg, 256, 0, stream>>>(v, wob, out, M, N, K);
}